// Round 1
// baseline (2831.450 us; speedup 1.0000x reference)
//
#include <hip/hip_runtime.h>
#include <hip/hip_bf16.h>

#define BS 32
#define C 128
#define NH 4
#define HD 32
#define XSTR 129   // fp32 LDS stride: (129*i + c) % 32 distinct across i -> conflict-free
#define QSTR 130   // bf16 LDS stride: byte 260*i -> bank 65*i % 32 distinct across i

typedef unsigned long long ull;

// Pass 1: for each in-block off-diagonal edge, atomicMax a packed key so that the
// HIGHEST edge index wins (numpy last-write-wins semantics). Low 32 bits carry the
// edge value's float bits; word==0 means "no edge" (mask 0).
__global__ void edge_scatter_kernel(const int* __restrict__ rows,
                                    const int* __restrict__ cols,
                                    const float* __restrict__ vals,
                                    ull* __restrict__ packed, int E) {
    int stride = gridDim.x * blockDim.x;
    for (int e = blockIdx.x * blockDim.x + threadIdx.x; e < E; e += stride) {
        int r = rows[e], c = cols[e];
        if ((r >> 5) != (c >> 5)) continue;          // not in same 32-block
        int rl = r & 31, cl = c & 31;
        if (rl == cl) continue;                      // diagonal overridden to 1.0 later
        ull key = ((ull)(unsigned)(e + 1) << 32) | (ull)__float_as_uint(vals[e]);
        atomicMax(&packed[((size_t)(r >> 5) * BS + rl) * (BS + 1) + cl], key);
    }
}

// One workgroup (256 thr = 4 waves) per 32-node block.
// Phases: load x -> mean -> QKV (fp32 acc, bf16 LDS stage) -> per-head attention
// (wave w = head w) -> PV -> proj -> store. ao reuses the xs buffer.
__global__ __launch_bounds__(256)
void block_attn_kernel(const float* __restrict__ x,
                       const ull* __restrict__ packed,
                       const float* __restrict__ qkv_w,
                       const float* __restrict__ qkv_b,
                       const float* __restrict__ proj_w,
                       const float* __restrict__ proj_b,
                       const float* __restrict__ gate_w,
                       const float* __restrict__ gate_b,
                       float* __restrict__ out) {
    __shared__ float xs[BS + 1][XSTR];           // x rows + mean row; reused as attn-out
    __shared__ __hip_bfloat16 qs[BS][QSTR];
    __shared__ __hip_bfloat16 ks[BS + 1][QSTR];
    __shared__ __hip_bfloat16 vs[BS + 1][QSTR];

    const int b = blockIdx.x;
    const int t = threadIdx.x;
    const float* xb = x + (size_t)b * BS * C;

    // ---- load x block (coalesced float4) ----
    for (int idx = t * 4; idx < BS * C; idx += 256 * 4) {
        const float4 v = *(const float4*)(xb + idx);
        int i = idx >> 7, cc = idx & 127;
        xs[i][cc] = v.x; xs[i][cc + 1] = v.y; xs[i][cc + 2] = v.z; xs[i][cc + 3] = v.w;
    }
    __syncthreads();

    // ---- mean row (block node) ----
    if (t < C) {
        float s = 0.f;
        #pragma unroll
        for (int i = 0; i < BS; ++i) s += xs[i][t];
        xs[BS][t] = s * (1.f / 32.f);
    }
    __syncthreads();

    // ---- QKV: waves 0-1 (t<128) compute q-col t and v-col t; waves 2-3 compute k-col t-128 ----
    if (t < 128) {
        float accQ[BS]; float accV[BS + 1];
        #pragma unroll
        for (int i = 0; i < BS; ++i) accQ[i] = 0.f;
        #pragma unroll
        for (int i = 0; i < BS + 1; ++i) accV[i] = 0.f;
        #pragma unroll 2
        for (int kk = 0; kk < C; ++kk) {
            float wq = qkv_w[kk * 384 + t];
            float wv = qkv_w[kk * 384 + 256 + t];
            #pragma unroll
            for (int i = 0; i < BS; ++i) { float s = xs[i][kk]; accQ[i] += s * wq; accV[i] += s * wv; }
            accV[BS] += xs[BS][kk] * wv;
        }
        float bq = qkv_b[t], bv = qkv_b[256 + t];
        #pragma unroll
        for (int i = 0; i < BS; ++i) qs[i][t] = __float2bfloat16(accQ[i] + bq);
        #pragma unroll
        for (int i = 0; i < BS + 1; ++i) vs[i][t] = __float2bfloat16(accV[i] + bv);
    } else {
        float accK[BS + 1];
        #pragma unroll
        for (int i = 0; i < BS + 1; ++i) accK[i] = 0.f;
        #pragma unroll 2
        for (int kk = 0; kk < C; ++kk) {
            float wk = qkv_w[kk * 384 + t];   // t in [128,256) -> k columns
            #pragma unroll
            for (int i = 0; i < BS + 1; ++i) accK[i] += xs[i][kk] * wk;
        }
        float bk = qkv_b[t];
        #pragma unroll
        for (int i = 0; i < BS + 1; ++i) ks[i][t - 128] = __float2bfloat16(accK[i] + bk);
    }
    __syncthreads();

    // ---- attention: wave h handles head h; lane = 32*half + i; lane covers j = half+2*jj ----
    {
        const int h    = t >> 6;
        const int lane = t & 63;
        const int i    = lane & 31;
        const int half = lane >> 5;
        const float scale = 0.17677669529663687f;   // 32^-0.5

        float qreg[HD];
        #pragma unroll
        for (int kk = 0; kk < HD; ++kk) qreg[kk] = __bfloat162float(qs[i][h * HD + kk]);

        float sc[17], gt[17];
        const float gwh = gate_w[h];
        const float gbh = gate_b[h];
        const ull* pb = packed + ((size_t)b * BS + i) * (BS + 1);

        float mx = -3.0e38f;
        #pragma unroll
        for (int jj = 0; jj < 17; ++jj) {
            int j = half + 2 * jj;
            float s, g;
            if (j <= BS) {
                float d = 0.f;
                #pragma unroll
                for (int kk = 0; kk < HD; ++kk) d += qreg[kk] * __bfloat162float(ks[j][h * HD + kk]);
                float wb; bool msk;
                if (j == BS || j == i) { wb = 1.f; msk = true; }
                else {
                    ull w = pb[j];
                    msk = (w != 0ull);
                    wb = __uint_as_float((unsigned)(w & 0xffffffffu));
                }
                s = msk ? d * scale + wb : -1.0e9f;
                g = msk ? wb * gwh + gbh : 0.f;
            } else { s = -3.0e38f; g = 0.f; }
            sc[jj] = s; gt[jj] = g;
            mx = fmaxf(mx, s);
        }
        mx = fmaxf(mx, __shfl_xor(mx, 32, 64));
        float sum = 0.f;
        #pragma unroll
        for (int jj = 0; jj < 17; ++jj) { float e = expf(sc[jj] - mx); sc[jj] = e; sum += e; }
        sum += __shfl_xor(sum, 32, 64);
        const float inv = 1.f / sum;

        float acc[HD];
        #pragma unroll
        for (int d = 0; d < HD; ++d) acc[d] = 0.f;
        #pragma unroll
        for (int jj = 0; jj < 17; ++jj) {
            int j = half + 2 * jj;
            if (j <= BS) {
                float cmb = sc[jj] * inv + gt[jj];
                #pragma unroll
                for (int d = 0; d < HD; ++d) acc[d] += cmb * __bfloat162float(vs[j][h * HD + d]);
            }
        }
        #pragma unroll
        for (int d = 0; d < HD; ++d) acc[d] += __shfl_xor(acc[d], 32, 64);
        // both halves now hold the full row; half 0 writes attn-out into xs (x is dead)
        if (half == 0) {
            #pragma unroll
            for (int d = 0; d < HD; ++d) xs[i][h * HD + d] = acc[d];
        }
    }
    __syncthreads();

    // ---- proj: thread t -> out col j = t&127, rows [(t>>7)*16, +16) ----
    {
        const int j  = t & 127;
        const int rb = (t >> 7) * 16;
        float acc2[16];
        const float pbias = proj_b[j];
        #pragma unroll
        for (int r = 0; r < 16; ++r) acc2[r] = pbias;
        #pragma unroll 2
        for (int kk = 0; kk < C; ++kk) {
            float w = proj_w[kk * C + j];
            #pragma unroll
            for (int r = 0; r < 16; ++r) acc2[r] += xs[rb + r][kk] * w;
        }
        float* ob = out + ((size_t)b * BS + rb) * C + j;
        #pragma unroll
        for (int r = 0; r < 16; ++r) ob[(size_t)r * C] = acc2[r];
    }
}

extern "C" void kernel_launch(void* const* d_in, const int* in_sizes, int n_in,
                              void* d_out, int out_size, void* d_ws, size_t ws_size,
                              hipStream_t stream) {
    const float* x      = (const float*)d_in[0];
    const int*   ei     = (const int*)d_in[1];
    const float* ev     = (const float*)d_in[2];
    // d_in[3] = positions: dx features are never used by the reference output -> skipped
    const float* qkv_w  = (const float*)d_in[4];
    const float* qkv_b  = (const float*)d_in[5];
    const float* proj_w = (const float*)d_in[6];
    const float* proj_b = (const float*)d_in[7];
    const float* gate_w = (const float*)d_in[8];
    const float* gate_b = (const float*)d_in[9];
    float* out = (float*)d_out;

    const int E  = in_sizes[2];
    const int N  = in_sizes[0] / C;
    const int nb = N / BS;

    ull* packed = (ull*)d_ws;
    size_t pbytes = (size_t)nb * BS * (BS + 1) * sizeof(ull);
    hipMemsetAsync(packed, 0, pbytes, stream);

    edge_scatter_kernel<<<2048, 256, 0, stream>>>(ei, ei + E, ev, packed, E);
    block_attn_kernel<<<nb, 256, 0, stream>>>(x, packed, qkv_w, qkv_b,
                                              proj_w, proj_b, gate_w, gate_b, out);
}

// Round 2
// 248.578 us; speedup vs baseline: 11.3906x; 11.3906x over previous
//
#include <hip/hip_runtime.h>
#include <hip/hip_bf16.h>

#define BS 32
#define NBC 33   // BS+1 columns in the packed edge table

typedef unsigned long long ull;
typedef __attribute__((ext_vector_type(8))) __bf16 bf16x8;
typedef __attribute__((ext_vector_type(4))) float f32x4;
typedef __attribute__((ext_vector_type(4))) unsigned short us4;

__device__ __forceinline__ unsigned short f2b(float f) {
    __hip_bfloat16 h = __float2bfloat16(f);
    return *reinterpret_cast<unsigned short*>(&h);
}
__device__ __forceinline__ float b2f(unsigned short u) {
    union { unsigned int i; float f; } x; x.i = ((unsigned int)u) << 16; return x.f;
}
#define LD8(p) (*reinterpret_cast<const bf16x8*>(p))

// ---------------- pass 1: last-edge-wins scatter of in-block edges ----------------
__global__ void edge_scatter_kernel(const int* __restrict__ rows,
                                    const int* __restrict__ cols,
                                    const float* __restrict__ vals,
                                    ull* __restrict__ packed, int E) {
    int stride = gridDim.x * blockDim.x;
    for (int e = blockIdx.x * blockDim.x + threadIdx.x; e < E; e += stride) {
        int r = rows[e], c = cols[e];
        if ((r >> 5) != (c >> 5)) continue;
        int rl = r & 31, cl = c & 31;
        if (rl == cl) continue;                      // diagonal overridden to 1.0 later
        ull key = ((ull)(unsigned)(e + 1) << 32) | (ull)__float_as_uint(vals[e]);
        atomicMax(&packed[((size_t)(r >> 5) * BS + rl) * NBC + cl], key);
    }
}

// ---------------- pass 2: repack weights into MFMA B-fragment order ----------------
// frag f: lane l holds B[k = (f&3)*32 + (l>>4)*8 + j][n = (f>>2)*16 + (l&15)], j=0..7
// qkv_w: 24 ntiles x 4 ksteps = 96 frags; proj_w: 8 x 4 = 32 frags. 512 bf16 per frag.
__global__ void prepack_kernel(const float* __restrict__ qkv_w,
                               const float* __restrict__ proj_w,
                               unsigned short* __restrict__ wq,
                               unsigned short* __restrict__ wp) {
    int tid = blockIdx.x * 256 + threadIdx.x;        // 0 .. 65535
    int f = tid >> 9, lane = (tid >> 3) & 63, j = tid & 7;
    int kk = (f & 3) * 32 + (lane >> 4) * 8 + j;
    int nn = lane & 15;
    if (f < 96) {
        int nt = f >> 2;
        wq[tid] = f2b(qkv_w[kk * 384 + nt * 16 + nn]);
    } else {
        int f2 = f - 96;
        int nt = f2 >> 2;
        wp[f2 * 512 + lane * 8 + j] = f2b(proj_w[kk * 128 + nt * 16 + nn]);
    }
}

// ---------------- main fused kernel: one 4-wave WG per 32-node block ----------------
__global__ __launch_bounds__(256)
void block_attn_kernel(const float* __restrict__ x,
                       const ull* __restrict__ packed,
                       const unsigned short* __restrict__ wq,
                       const unsigned short* __restrict__ wp,
                       const float* __restrict__ qkv_b,
                       const float* __restrict__ proj_b,
                       const float* __restrict__ gate_w,
                       const float* __restrict__ gate_b,
                       float* __restrict__ out) {
    // strides: 136 ush = 272 B (16B-aligned, <=2-way banks); 40 ush = 80 B likewise
    __shared__ __align__(16) unsigned short xs[32][136];   // x (bf16); reused as attn-out
    __shared__ __align__(16) unsigned short qsm[32][136];
    __shared__ __align__(16) unsigned short ksm[34][136];  // rows 0-31 + mean(32) + zero(33)
    __shared__ __align__(16) unsigned short vT[128][40];   // transposed V: [dim][kvrow], col 32 = mean
    __shared__ __align__(16) unsigned short pbuf[4][32][40]; // per-head P (combined), cols 0-31
    __shared__ float pcol[4][32];                          // P column 32 (block node), fp32

    const int b = blockIdx.x;
    const int t = threadIdx.x;
    const int w = t >> 6, l = t & 63, g16 = l >> 4, c16 = l & 15;

    // ---- phase 0: stage x block as bf16 ----
    const float* xb = x + (size_t)b * (BS * 128);
    #pragma unroll
    for (int it = 0; it < 4; ++it) {
        int idx = (t + it * 256) * 4;
        float4 v = *reinterpret_cast<const float4*>(xb + idx);
        us4 u; u.x = f2b(v.x); u.y = f2b(v.y); u.z = f2b(v.z); u.w = f2b(v.w);
        *reinterpret_cast<us4*>(&xs[idx >> 7][idx & 127]) = u;
    }
    if (t < 136) ksm[33][t] = 0;   // zero pad row (clamp target for n>33)
    __syncthreads();

    // ---- phase 1: QKV GEMM (M=32, K=128, N=384), wave w owns cols [96w, 96w+96) ----
    {
        bf16x8 a[2][4];
        #pragma unroll
        for (int mt = 0; mt < 2; ++mt)
            #pragma unroll
            for (int ks = 0; ks < 4; ++ks)
                a[mt][ks] = LD8(&xs[c16 + 16 * mt][ks * 32 + g16 * 8]);

        const unsigned short* wqs = wq + (size_t)(w * 24) * 512 + l * 8;
        bf16x8 bn[4];
        #pragma unroll
        for (int ks = 0; ks < 4; ++ks) bn[ks] = LD8(wqs + ks * 512);

        #pragma unroll
        for (int nt = 0; nt < 6; ++nt) {
            bf16x8 bc[4];
            #pragma unroll
            for (int ks = 0; ks < 4; ++ks) bc[ks] = bn[ks];
            if (nt < 5) {
                #pragma unroll
                for (int ks = 0; ks < 4; ++ks) bn[ks] = LD8(wqs + ((nt + 1) * 4 + ks) * 512);
            }
            f32x4 acc0 = {0.f, 0.f, 0.f, 0.f}, acc1 = {0.f, 0.f, 0.f, 0.f};
            #pragma unroll
            for (int ks = 0; ks < 4; ++ks) {
                acc0 = __builtin_amdgcn_mfma_f32_16x16x32_bf16(a[0][ks], bc[ks], acc0, 0, 0, 0);
                acc1 = __builtin_amdgcn_mfma_f32_16x16x32_bf16(a[1][ks], bc[ks], acc1, 0, 0, 0);
            }
            const int colg = 96 * w + 16 * nt + c16;
            const float bias = qkv_b[colg];
            // column sum over all 32 rows -> mean row (k/v of the block node)
            float csum = acc0[0] + acc0[1] + acc0[2] + acc0[3]
                       + acc1[0] + acc1[1] + acc1[2] + acc1[3];
            csum += __shfl_xor(csum, 16, 64);
            csum += __shfl_xor(csum, 32, 64);
            const float meanv = csum * (1.f / 32.f) + bias;
            if (colg < 128) {
                #pragma unroll
                for (int r = 0; r < 4; ++r) {
                    qsm[4 * g16 + r][colg]      = f2b(acc0[r] + bias);
                    qsm[16 + 4 * g16 + r][colg] = f2b(acc1[r] + bias);
                }
            } else if (colg < 256) {
                const int cc = colg - 128;
                #pragma unroll
                for (int r = 0; r < 4; ++r) {
                    ksm[4 * g16 + r][cc]      = f2b(acc0[r] + bias);
                    ksm[16 + 4 * g16 + r][cc] = f2b(acc1[r] + bias);
                }
                if (g16 == 0) ksm[32][cc] = f2b(meanv);
            } else {
                const int cc = colg - 256;
                #pragma unroll
                for (int r = 0; r < 4; ++r) {
                    vT[cc][4 * g16 + r]      = f2b(acc0[r] + bias);
                    vT[cc][16 + 4 * g16 + r] = f2b(acc1[r] + bias);
                }
                if (g16 == 0) vT[cc][32] = f2b(meanv);
            }
        }
    }
    __syncthreads();

    // ---- phase 2: attention, wave w = head w ----
    {
        const float scale = 0.17677669529663687f;   // 32^-0.5
        const float gwh = gate_w[w], gbh = gate_b[w];
        const int hb = w * 32;
        const f32x4 z4 = {0.f, 0.f, 0.f, 0.f};

        bf16x8 aq0 = LD8(&qsm[c16][hb + g16 * 8]);
        bf16x8 aq1 = LD8(&qsm[16 + c16][hb + g16 * 8]);
        bf16x8 bk[3];
        #pragma unroll
        for (int nt = 0; nt < 3; ++nt) {
            int n = 16 * nt + c16; if (n > 33) n = 33;   // pad cols read the zero row
            bk[nt] = LD8(&ksm[n][hb + g16 * 8]);
        }
        f32x4 s[2][3];
        #pragma unroll
        for (int nt = 0; nt < 3; ++nt) {
            s[0][nt] = __builtin_amdgcn_mfma_f32_16x16x32_bf16(aq0, bk[nt], z4, 0, 0, 0);
            s[1][nt] = __builtin_amdgcn_mfma_f32_16x16x32_bf16(aq1, bk[nt], z4, 0, 0, 0);
        }

        const ull* pbb = packed + (size_t)b * (BS * NBC);
        float cmb[2][3][4];
        #pragma unroll
        for (int mt = 0; mt < 2; ++mt) {
            #pragma unroll
            for (int r = 0; r < 4; ++r) {
                const int i = 16 * mt + 4 * g16 + r;
                float sc[3], gt[3];
                #pragma unroll
                for (int nt = 0; nt < 2; ++nt) {
                    const int j = 16 * nt + c16;
                    const ull wv = pbb[i * NBC + j];
                    const bool diag = (j == i);
                    const bool m = diag || (wv != 0ull);
                    const float wb = diag ? 1.f : __uint_as_float((unsigned)wv);
                    const float d = s[mt][nt][r] * scale;
                    sc[nt] = m ? d + wb : -1.0e9f;
                    gt[nt] = m ? wb * gwh + gbh : 0.f;
                }
                if (c16 == 0) { sc[2] = s[mt][2][r] * scale + 1.f; gt[2] = gwh + gbh; }
                else          { sc[2] = -1.0e9f;                   gt[2] = 0.f; }

                float mx = fmaxf(fmaxf(sc[0], sc[1]), sc[2]);
                mx = fmaxf(mx, __shfl_xor(mx, 1, 64));
                mx = fmaxf(mx, __shfl_xor(mx, 2, 64));
                mx = fmaxf(mx, __shfl_xor(mx, 4, 64));
                mx = fmaxf(mx, __shfl_xor(mx, 8, 64));
                float e0 = __expf(sc[0] - mx), e1 = __expf(sc[1] - mx), e2 = __expf(sc[2] - mx);
                float sum = e0 + e1 + e2;
                sum += __shfl_xor(sum, 1, 64);
                sum += __shfl_xor(sum, 2, 64);
                sum += __shfl_xor(sum, 4, 64);
                sum += __shfl_xor(sum, 8, 64);
                const float inv = __builtin_amdgcn_rcpf(sum);
                cmb[mt][0][r] = e0 * inv + gt[0];
                cmb[mt][1][r] = e1 * inv + gt[1];
                cmb[mt][2][r] = e2 * inv + gt[2];
            }
        }
        // stage P (combined = probs + gate) for PV
        #pragma unroll
        for (int mt = 0; mt < 2; ++mt)
            #pragma unroll
            for (int r = 0; r < 4; ++r) {
                const int i = 16 * mt + 4 * g16 + r;
                pbuf[w][i][c16]      = f2b(cmb[mt][0][r]);
                pbuf[w][i][16 + c16] = f2b(cmb[mt][1][r]);
                if (c16 == 0) pcol[w][i] = cmb[mt][2][r];
            }

        // PV over kv rows 0-31 via MFMA; block-node row via rank-1 update
        bf16x8 ap0 = LD8(&pbuf[w][c16][g16 * 8]);
        bf16x8 ap1 = LD8(&pbuf[w][16 + c16][g16 * 8]);
        f32x4 o[2][2];
        #pragma unroll
        for (int nt = 0; nt < 2; ++nt) {
            bf16x8 bv = LD8(&vT[hb + 16 * nt + c16][g16 * 8]);
            o[0][nt] = __builtin_amdgcn_mfma_f32_16x16x32_bf16(ap0, bv, z4, 0, 0, 0);
            o[1][nt] = __builtin_amdgcn_mfma_f32_16x16x32_bf16(ap1, bv, z4, 0, 0, 0);
        }
        #pragma unroll
        for (int nt = 0; nt < 2; ++nt) {
            const float vm = b2f(vT[hb + 16 * nt + c16][32]);
            #pragma unroll
            for (int mt = 0; mt < 2; ++mt)
                #pragma unroll
                for (int r = 0; r < 4; ++r)
                    o[mt][nt][r] += pcol[w][16 * mt + 4 * g16 + r] * vm;
        }
        // write attn-out into xs (x is dead); wave-disjoint cols [32w, 32w+32)
        #pragma unroll
        for (int mt = 0; mt < 2; ++mt)
            #pragma unroll
            for (int nt = 0; nt < 2; ++nt)
                #pragma unroll
                for (int r = 0; r < 4; ++r)
                    xs[16 * mt + 4 * g16 + r][hb + 16 * nt + c16] = f2b(o[mt][nt][r]);
    }
    __syncthreads();

    // ---- phase 3: projection (M=32, K=128, N=128), wave w owns cols [32w, 32w+32) ----
    {
        const f32x4 z4 = {0.f, 0.f, 0.f, 0.f};
        bf16x8 aa[2][4];
        #pragma unroll
        for (int mt = 0; mt < 2; ++mt)
            #pragma unroll
            for (int ks = 0; ks < 4; ++ks)
                aa[mt][ks] = LD8(&xs[c16 + 16 * mt][ks * 32 + g16 * 8]);

        f32x4 po[2][2];
        po[0][0] = z4; po[0][1] = z4; po[1][0] = z4; po[1][1] = z4;
        const unsigned short* wps = wp + (size_t)(w * 8) * 512 + l * 8;
        #pragma unroll
        for (int nt = 0; nt < 2; ++nt)
            #pragma unroll
            for (int ks = 0; ks < 4; ++ks) {
                bf16x8 bw = LD8(wps + (nt * 4 + ks) * 512);
                po[0][nt] = __builtin_amdgcn_mfma_f32_16x16x32_bf16(aa[0][ks], bw, po[0][nt], 0, 0, 0);
                po[1][nt] = __builtin_amdgcn_mfma_f32_16x16x32_bf16(aa[1][ks], bw, po[1][nt], 0, 0, 0);
            }
        float* ob = out + (size_t)b * (BS * 128);
        #pragma unroll
        for (int nt = 0; nt < 2; ++nt) {
            const int col = 32 * w + 16 * nt + c16;
            const float pbv = proj_b[col];
            #pragma unroll
            for (int mt = 0; mt < 2; ++mt)
                #pragma unroll
                for (int r = 0; r < 4; ++r)
                    ob[(size_t)(16 * mt + 4 * g16 + r) * 128 + col] = po[mt][nt][r] + pbv;
        }
    }
}

extern "C" void kernel_launch(void* const* d_in, const int* in_sizes, int n_in,
                              void* d_out, int out_size, void* d_ws, size_t ws_size,
                              hipStream_t stream) {
    const float* x      = (const float*)d_in[0];
    const int*   ei     = (const int*)d_in[1];
    const float* ev     = (const float*)d_in[2];
    // d_in[3] = positions: unused by the reference output
    const float* qkv_w  = (const float*)d_in[4];
    const float* qkv_b  = (const float*)d_in[5];
    const float* proj_w = (const float*)d_in[6];
    const float* proj_b = (const float*)d_in[7];
    const float* gate_w = (const float*)d_in[8];
    const float* gate_b = (const float*)d_in[9];
    float* out = (float*)d_out;

    const int E  = in_sizes[2];
    const int N  = in_sizes[0] / 128;
    const int nb = N / BS;

    ull* packed = (ull*)d_ws;
    size_t pbytes = (size_t)nb * BS * NBC * sizeof(ull);
    unsigned short* wqp = (unsigned short*)((char*)d_ws + pbytes);
    unsigned short* wpp = wqp + 96 * 512;

    hipMemsetAsync(packed, 0, pbytes, stream);
    prepack_kernel<<<256, 256, 0, stream>>>(qkv_w, proj_w, wqp, wpp);
    edge_scatter_kernel<<<2048, 256, 0, stream>>>(ei, ei + E, ev, packed, E);
    block_attn_kernel<<<nb, 256, 0, stream>>>(x, packed, wqp, wpp, qkv_b, proj_b,
                                              gate_w, gate_b, out);
}